// Round 12
// baseline (397.668 us; speedup 1.0000x reference)
//
#include <hip/hip_runtime.h>

#define NTOK 262144   // 64*64*64 tokens per batch
#define NCH  64
#define NB   4

#define TPB   512     // 8 waves
#define TILE  256     // tokens per tile (64 lanes x 4 tokens)
#define GRIDX 256     // blocks per batch -> 1024 total = 4/CU  (TLP: hide barrier/exp phases)
#define NIT   (NTOK / (GRIDX * TILE))   // 4 consecutive tiles per block

// ws layout (floats): S[4][4] @0, m[4][4][64] @16, rc[4][64] @1040
#define WS_S  0
#define WS_M  16
#define WS_RC 1040

// kpart slot stride in float4s (64 lanes + 2 pad)
#define KPS 66

typedef float floatx4 __attribute__((ext_vector_type(4)));   // native vec for nontemporal

// Single-x-read fused reduce, 1KB-extent loads, 4 blocks/CU.
// Wave w owns channels [8w, 8w+8); lane l owns tokens 4l..4l+3 (float4) of the
// 256-token tile; every load instruction covers 1KB contiguous.
// Keys: per-wave partial kk -> kpart LDS -> exp phase (waves 0-3) -> es LDS ->
// phase B accumulates m in registers (macc[32], static indexing only).
// VGPR ~64 (r11 measured) -> 32 waves/CU allowed; LDS 39.4KB -> 4 blocks/CU.
// While one block sits in barrier/exp, another block's loads stream (r4-keys
// evidence: this pattern sustains ~2.6TB/s when the memory pipe never idles).
__global__ __launch_bounds__(TPB)
void ea3d_reduce(const float* __restrict__ x, const float* __restrict__ Wk,
                 float* __restrict__ ws)
{
    __shared__ __align__(16) float wk4[NCH * 4];          // wk4[c][h]
    __shared__ __align__(16) float kpart[32 * KPS * 4];   // [w][j] slots of KPS float4
    __shared__ __align__(16) float es[4 * 64 * 4];        // [j][lane][h]
    __shared__ float ssum[4][4];

    const int tid = threadIdx.x;
    const int w   = tid >> 6;
    const int l   = tid & 63;
    const int b   = blockIdx.y;

    if (tid < 256) { int c = tid >> 2, h = tid & 3; wk4[(c << 2) + h] = Wk[h * NCH + c]; }
    __syncthreads();

    const int c0 = w << 3;                        // this wave's 8 channels
    const float* xb = x + ((size_t)b * NCH + c0) * NTOK;
    const size_t tokbase = (size_t)blockIdx.x * (TILE * NIT) + (l << 2);

    float macc[32];                               // macc[i*4+h], channel c0+i
    #pragma unroll
    for (int r = 0; r < 32; ++r) macc[r] = 0.f;
    float4 sacc4 = make_float4(0.f, 0.f, 0.f, 0.f);

    float4* kp = (float4*)kpart;

    for (int it = 0; it < NIT; ++it) {
        // ---- phase A: 8 x 1KB loads (this wave's channels, lane's 4 tokens) ----
        const float* xp = xb + tokbase + (size_t)it * TILE;
        float4 xr[8];
        #pragma unroll
        for (int i = 0; i < 8; ++i)
            xr[i] = *(const float4*)(xp + (size_t)i * NTOK);

        float kk[16];                             // kk[j*4+h], token j, head h
        #pragma unroll
        for (int r = 0; r < 16; ++r) kk[r] = 0.f;
        #pragma unroll
        for (int i = 0; i < 8; ++i) {
            float4 wv = *((const float4*)wk4 + (c0 + i));
            kk[0]  += wv.x * xr[i].x; kk[1]  += wv.y * xr[i].x;
            kk[2]  += wv.z * xr[i].x; kk[3]  += wv.w * xr[i].x;
            kk[4]  += wv.x * xr[i].y; kk[5]  += wv.y * xr[i].y;
            kk[6]  += wv.z * xr[i].y; kk[7]  += wv.w * xr[i].y;
            kk[8]  += wv.x * xr[i].z; kk[9]  += wv.y * xr[i].z;
            kk[10] += wv.z * xr[i].z; kk[11] += wv.w * xr[i].z;
            kk[12] += wv.x * xr[i].w; kk[13] += wv.y * xr[i].w;
            kk[14] += wv.z * xr[i].w; kk[15] += wv.w * xr[i].w;
        }
        #pragma unroll
        for (int j = 0; j < 4; ++j)               // contiguous lane-stride writes
            kp[((w << 2) + j) * KPS + l] =
                make_float4(kk[j*4+0], kk[j*4+1], kk[j*4+2], kk[j*4+3]);

        asm volatile("s_waitcnt lgkmcnt(0)" ::: "memory");
        __builtin_amdgcn_s_barrier();             // kpart ready (vmcnt NOT drained)
        asm volatile("" ::: "memory");

        // ---- exp phase: waves 0-3, thread -> one token, all 4 heads ----
        if (tid < 256) {
            const int jj = tid & 3, lw = tid >> 2;
            float4 p = make_float4(0.f, 0.f, 0.f, 0.f);
            #pragma unroll
            for (int w2 = 0; w2 < 8; ++w2) {
                float4 qv = kp[((w2 << 2) + jj) * KPS + lw];
                p.x += qv.x; p.y += qv.y; p.z += qv.z; p.w += qv.w;
            }
            float4 e4 = make_float4(__expf(p.x), __expf(p.y), __expf(p.z), __expf(p.w));
            *(float4*)(es + ((jj << 6) + lw) * 4) = e4;
            sacc4.x += e4.x; sacc4.y += e4.y; sacc4.z += e4.z; sacc4.w += e4.w;
        }

        asm volatile("s_waitcnt lgkmcnt(0)" ::: "memory");
        __builtin_amdgcn_s_barrier();             // es ready
        asm volatile("" ::: "memory");

        // ---- phase B: m accumulation (registers, static) ----
        {
            float4 e0 = *(const float4*)(es + ((0 << 6) + l) * 4);
            float4 e1 = *(const float4*)(es + ((1 << 6) + l) * 4);
            float4 e2 = *(const float4*)(es + ((2 << 6) + l) * 4);
            float4 e3 = *(const float4*)(es + ((3 << 6) + l) * 4);
            #pragma unroll
            for (int i = 0; i < 8; ++i) {
                macc[i*4+0] += e0.x*xr[i].x + e1.x*xr[i].y + e2.x*xr[i].z + e3.x*xr[i].w;
                macc[i*4+1] += e0.y*xr[i].x + e1.y*xr[i].y + e2.y*xr[i].z + e3.y*xr[i].w;
                macc[i*4+2] += e0.z*xr[i].x + e1.z*xr[i].y + e2.z*xr[i].z + e3.z*xr[i].w;
                macc[i*4+3] += e0.w*xr[i].x + e1.w*xr[i].y + e2.w*xr[i].z + e3.w*xr[i].w;
            }
        }
        // next tile's kpart writes are ordered after barrier2 for all waves;
        // es is rewritten only after the NEXT barrier1 -> safe.
    }

    // ---- macc: reduce over this wave's 64 lanes (token dim), atomics per wave ----
    #pragma unroll
    for (int r = 0; r < 32; ++r) {
        float v = macc[r];
        v += __shfl_xor(v, 1);  v += __shfl_xor(v, 2);
        v += __shfl_xor(v, 4);  v += __shfl_xor(v, 8);
        v += __shfl_xor(v, 16); v += __shfl_xor(v, 32);
        macc[r] = v;
    }
    if (l == 0) {
        float* mb = ws + WS_M + (size_t)(b * 4) * NCH + c0;
        #pragma unroll
        for (int i = 0; i < 8; ++i) {
            #pragma unroll
            for (int h = 0; h < 4; ++h)
                __hip_atomic_fetch_add(mb + h * NCH + i, macc[i*4+h],
                                       __ATOMIC_RELAXED, __HIP_MEMORY_SCOPE_AGENT);
        }
    }

    // ---- S: waves 0-3 hold per-token e-sums (float4 over heads) ----
    if (w < 4) {
        float4 v = sacc4;
        #pragma unroll
        for (int off = 32; off; off >>= 1) {
            v.x += __shfl_xor(v.x, off); v.y += __shfl_xor(v.y, off);
            v.z += __shfl_xor(v.z, off); v.w += __shfl_xor(v.w, off);
        }
        if (l == 0) { ssum[w][0] = v.x; ssum[w][1] = v.y; ssum[w][2] = v.z; ssum[w][3] = v.w; }
    }
    __syncthreads();
    if (tid < 4) {
        float s = (ssum[0][tid] + ssum[1][tid]) + (ssum[2][tid] + ssum[3][tid]);
        __hip_atomic_fetch_add(ws + WS_S + b * 4 + tid, s,
                               __ATOMIC_RELAXED, __HIP_MEMORY_SCOPE_AGENT);
    }
}

// ---------- finalize: context = Wv*(m/S)+bv ; rc = Wr*context + br ----------
__global__ void ea3d_finalize(const float* __restrict__ Wv, const float* __restrict__ bv,
                              const float* __restrict__ Wr, const float* __restrict__ br,
                              float* __restrict__ ws)
{
    __shared__ float ctx[NB * 32];
    const int tid = threadIdx.x;
    if (tid < 128) {
        int b = tid >> 5, hv = tid & 31, h = hv >> 3;
        float inv = 1.0f / ws[WS_S + b * 4 + h];
        const float* m = ws + WS_M + (b * 4 + h) * NCH;
        const float* wvr = Wv + hv * NCH;
        float acc = 0.f;
        #pragma unroll
        for (int c = 0; c < NCH; ++c) acc += wvr[c] * m[c];
        ctx[b * 32 + hv] = acc * inv + bv[hv];
    }
    __syncthreads();
    int b = tid >> 6, c = tid & 63;
    const float* wrr = Wr + c * 32;
    const float* cb  = ctx + b * 32;
    float acc = br[c];
    #pragma unroll
    for (int hv = 0; hv < 32; ++hv) acc += wrr[hv] * cb[hv];
    ws[WS_RC + b * NCH + c] = acc;
}

// ---------- out = x + rc[b][c]  (nontemporal stores: don't evict x) ----------
__global__ __launch_bounds__(256)
void ea3d_add(const float* __restrict__ x, const float* __restrict__ ws,
              float* __restrict__ out)
{
    const int row = blockIdx.y;                 // b*64 + c
    const float rc = ws[WS_RC + row];
    const size_t base = (size_t)row * NTOK;
    const float4*  xp = (const float4*)(x + base);
    floatx4*       op = (floatx4*)(out + base);
    const int nvec = NTOK / 4;
    for (int i = blockIdx.x * blockDim.x + threadIdx.x; i < nvec;
         i += gridDim.x * blockDim.x) {
        float4 v = xp[i];
        floatx4 nv = { v.x + rc, v.y + rc, v.z + rc, v.w + rc };
        __builtin_nontemporal_store(nv, op + i);
    }
}

extern "C" void kernel_launch(void* const* d_in, const int* in_sizes, int n_in,
                              void* d_out, int out_size, void* d_ws, size_t ws_size,
                              hipStream_t stream)
{
    const float* x  = (const float*)d_in[0];
    const float* Wk = (const float*)d_in[1];
    // d_in[2]=bk (cancels in token-softmax); d_in[3]=Wq, d_in[4]=bq (softmax over
    // size-1 head-channel axis -> identically 1.0, so Wq/bq are dead)
    const float* Wv = (const float*)d_in[5];
    const float* bv = (const float*)d_in[6];
    const float* Wr = (const float*)d_in[7];
    const float* br = (const float*)d_in[8];
    float* out = (float*)d_out;
    float* ws  = (float*)d_ws;

    (void)hipMemsetAsync(ws, 0, WS_RC * sizeof(float), stream);  // zero S + m accumulators
    ea3d_reduce<<<dim3(GRIDX, NB), TPB, 0, stream>>>(x, Wk, ws);
    ea3d_finalize<<<1, 256, 0, stream>>>(Wv, bv, Wr, br, ws);
    ea3d_add<<<dim3(32, NB * NCH), 256, 0, stream>>>(x, ws, out);
}

// Round 13
// 220.189 us; speedup vs baseline: 1.8060x; 1.8060x over previous
//
#include <hip/hip_runtime.h>

#define NTOK 262144   // 64*64*64 tokens per batch
#define NCH  64
#define NB   4

#define TPB   512     // 8 waves
#define TILE  256     // tokens per tile (64 lanes x 4 tokens)
#define GRIDX 128     // blocks per batch -> 512 total = 2/CU (r11 shape; r12's 256 blew codegen)
#define NIT   (NTOK / (GRIDX * TILE))   // 8 consecutive tiles per block

// ws layout (floats): S[4][4] @0, m[4][4][64] @16, rc[4][64] @1040
#define WS_S  0
#define WS_M  16
#define WS_RC 1040

// kpart slot stride in float4s (64 lanes + 2 pad)
#define KPS 66

typedef float floatx4 __attribute__((ext_vector_type(4)));   // native vec for nontemporal

// Single-x-read fused reduce, 1KB-extent loads, register-ping-pong prefetch.
// Wave w owns channels [8w, 8w+8); lane l owns tokens 4l..4l+3 (float4).
// Per tile: kk consumes cur -> ISSUE next tile's 8 loads (stay in flight
// across both raw barriers: vmcnt NOT drained) -> kpart -> b1 -> exp -> b2 ->
// phase B (cur) -> swap. This removes the inter-tile memory-idle bubble that
// capped r11 at ~890 GB/s while r4-keys (no barriers) hit ~2.6 TB/s.
// VGPR target ~96-110 (cur 32 + nxt 32 + kk 16 + macc 32 shared w/ kk window):
// under the 128 cliff -> 16 waves/CU. NIT=8 kept (r12 lesson: NIT=4 full-unroll
// blew VGPR to 116 and halved perf); outer loop pinned with #pragma unroll 1.
__global__ __launch_bounds__(TPB)
void ea3d_reduce(const float* __restrict__ x, const float* __restrict__ Wk,
                 float* __restrict__ ws)
{
    __shared__ __align__(16) float wk4[NCH * 4];          // wk4[c][h]
    __shared__ __align__(16) float kpart[32 * KPS * 4];   // [w][j] slots of KPS float4
    __shared__ __align__(16) float es[4 * 64 * 4];        // [j][lane][h]
    __shared__ float ssum[4][4];

    const int tid = threadIdx.x;
    const int w   = tid >> 6;
    const int l   = tid & 63;
    const int b   = blockIdx.y;

    if (tid < 256) { int c = tid >> 2, h = tid & 3; wk4[(c << 2) + h] = Wk[h * NCH + c]; }
    __syncthreads();

    const int c0 = w << 3;                        // this wave's 8 channels
    const float* xb = x + ((size_t)b * NCH + c0) * NTOK;
    const size_t tokbase = (size_t)blockIdx.x * (TILE * NIT) + (l << 2);

    float macc[32];                               // macc[i*4+h], channel c0+i
    #pragma unroll
    for (int r = 0; r < 32; ++r) macc[r] = 0.f;
    float4 sacc4 = make_float4(0.f, 0.f, 0.f, 0.f);

    float4* kp = (float4*)kpart;

    float4 xA[8], xB[8];
    {   // prologue: tile 0
        #pragma unroll
        for (int i = 0; i < 8; ++i)
            xA[i] = *(const float4*)(xb + (size_t)i * NTOK + tokbase);
    }

    auto body = [&](float4 (&cur)[8], float4 (&nxt)[8], int it) {
        // ---- keys partial (8 channels x lane's 4 tokens) ----
        float kk[16];                             // kk[j*4+h]
        #pragma unroll
        for (int r = 0; r < 16; ++r) kk[r] = 0.f;
        #pragma unroll
        for (int i = 0; i < 8; ++i) {
            float4 wv = *((const float4*)wk4 + (c0 + i));
            kk[0]  += wv.x * cur[i].x; kk[1]  += wv.y * cur[i].x;
            kk[2]  += wv.z * cur[i].x; kk[3]  += wv.w * cur[i].x;
            kk[4]  += wv.x * cur[i].y; kk[5]  += wv.y * cur[i].y;
            kk[6]  += wv.z * cur[i].y; kk[7]  += wv.w * cur[i].y;
            kk[8]  += wv.x * cur[i].z; kk[9]  += wv.y * cur[i].z;
            kk[10] += wv.z * cur[i].z; kk[11] += wv.w * cur[i].z;
            kk[12] += wv.x * cur[i].w; kk[13] += wv.y * cur[i].w;
            kk[14] += wv.z * cur[i].w; kk[15] += wv.w * cur[i].w;
        }

        // ---- prefetch next tile NOW; stays in flight across both barriers ----
        if (it + 1 < NIT) {
            const float* xp = xb + tokbase + (size_t)(it + 1) * TILE;
            #pragma unroll
            for (int i = 0; i < 8; ++i)
                nxt[i] = *(const float4*)(xp + (size_t)i * NTOK);
        }

        #pragma unroll
        for (int j = 0; j < 4; ++j)               // contiguous lane-stride writes
            kp[((w << 2) + j) * KPS + l] =
                make_float4(kk[j*4+0], kk[j*4+1], kk[j*4+2], kk[j*4+3]);

        asm volatile("s_waitcnt lgkmcnt(0)" ::: "memory");
        __builtin_amdgcn_s_barrier();             // kpart ready (vmcnt NOT drained)
        asm volatile("" ::: "memory");

        // ---- exp phase: waves 0-3, thread -> one token, all 4 heads ----
        if (tid < 256) {
            const int jj = tid & 3, lw = tid >> 2;
            float4 p = make_float4(0.f, 0.f, 0.f, 0.f);
            #pragma unroll
            for (int w2 = 0; w2 < 8; ++w2) {
                float4 qv = kp[((w2 << 2) + jj) * KPS + lw];
                p.x += qv.x; p.y += qv.y; p.z += qv.z; p.w += qv.w;
            }
            float4 e4 = make_float4(__expf(p.x), __expf(p.y), __expf(p.z), __expf(p.w));
            *(float4*)(es + ((jj << 6) + lw) * 4) = e4;
            sacc4.x += e4.x; sacc4.y += e4.y; sacc4.z += e4.z; sacc4.w += e4.w;
        }

        asm volatile("s_waitcnt lgkmcnt(0)" ::: "memory");
        __builtin_amdgcn_s_barrier();             // es ready
        asm volatile("" ::: "memory");

        // ---- phase B: m accumulation (registers, static) ----
        {
            float4 e0 = *(const float4*)(es + ((0 << 6) + l) * 4);
            float4 e1 = *(const float4*)(es + ((1 << 6) + l) * 4);
            float4 e2 = *(const float4*)(es + ((2 << 6) + l) * 4);
            float4 e3 = *(const float4*)(es + ((3 << 6) + l) * 4);
            #pragma unroll
            for (int i = 0; i < 8; ++i) {
                macc[i*4+0] += e0.x*cur[i].x + e1.x*cur[i].y + e2.x*cur[i].z + e3.x*cur[i].w;
                macc[i*4+1] += e0.y*cur[i].x + e1.y*cur[i].y + e2.y*cur[i].z + e3.y*cur[i].w;
                macc[i*4+2] += e0.z*cur[i].x + e1.z*cur[i].y + e2.z*cur[i].z + e3.z*cur[i].w;
                macc[i*4+3] += e0.w*cur[i].x + e1.w*cur[i].y + e2.w*cur[i].z + e3.w*cur[i].w;
            }
        }
        // next tile's kpart writes happen after barrier2 for all waves; es is
        // rewritten only between the NEXT b1/b2 -> safe.
    };

    #pragma unroll 1
    for (int it = 0; it < NIT; it += 2) {
        body(xA, xB, it);
        body(xB, xA, it + 1);
    }

    // ---- macc: reduce over this wave's 64 lanes (token dim), atomics per wave ----
    #pragma unroll
    for (int r = 0; r < 32; ++r) {
        float v = macc[r];
        v += __shfl_xor(v, 1);  v += __shfl_xor(v, 2);
        v += __shfl_xor(v, 4);  v += __shfl_xor(v, 8);
        v += __shfl_xor(v, 16); v += __shfl_xor(v, 32);
        macc[r] = v;
    }
    if (l == 0) {
        float* mb = ws + WS_M + (size_t)(b * 4) * NCH + c0;
        #pragma unroll
        for (int i = 0; i < 8; ++i) {
            #pragma unroll
            for (int h = 0; h < 4; ++h)
                __hip_atomic_fetch_add(mb + h * NCH + i, macc[i*4+h],
                                       __ATOMIC_RELAXED, __HIP_MEMORY_SCOPE_AGENT);
        }
    }

    // ---- S: waves 0-3 hold per-token e-sums (float4 over heads) ----
    if (w < 4) {
        float4 v = sacc4;
        #pragma unroll
        for (int off = 32; off; off >>= 1) {
            v.x += __shfl_xor(v.x, off); v.y += __shfl_xor(v.y, off);
            v.z += __shfl_xor(v.z, off); v.w += __shfl_xor(v.w, off);
        }
        if (l == 0) { ssum[w][0] = v.x; ssum[w][1] = v.y; ssum[w][2] = v.z; ssum[w][3] = v.w; }
    }
    __syncthreads();
    if (tid < 4) {
        float s = (ssum[0][tid] + ssum[1][tid]) + (ssum[2][tid] + ssum[3][tid]);
        __hip_atomic_fetch_add(ws + WS_S + b * 4 + tid, s,
                               __ATOMIC_RELAXED, __HIP_MEMORY_SCOPE_AGENT);
    }
}

// ---------- finalize: context = Wv*(m/S)+bv ; rc = Wr*context + br ----------
__global__ void ea3d_finalize(const float* __restrict__ Wv, const float* __restrict__ bv,
                              const float* __restrict__ Wr, const float* __restrict__ br,
                              float* __restrict__ ws)
{
    __shared__ float ctx[NB * 32];
    const int tid = threadIdx.x;
    if (tid < 128) {
        int b = tid >> 5, hv = tid & 31, h = hv >> 3;
        float inv = 1.0f / ws[WS_S + b * 4 + h];
        const float* m = ws + WS_M + (b * 4 + h) * NCH;
        const float* wvr = Wv + hv * NCH;
        float acc = 0.f;
        #pragma unroll
        for (int c = 0; c < NCH; ++c) acc += wvr[c] * m[c];
        ctx[b * 32 + hv] = acc * inv + bv[hv];
    }
    __syncthreads();
    int b = tid >> 6, c = tid & 63;
    const float* wrr = Wr + c * 32;
    const float* cb  = ctx + b * 32;
    float acc = br[c];
    #pragma unroll
    for (int hv = 0; hv < 32; ++hv) acc += wrr[hv] * cb[hv];
    ws[WS_RC + b * NCH + c] = acc;
}

// ---------- out = x + rc[b][c]  (nontemporal stores: don't evict x) ----------
__global__ __launch_bounds__(256)
void ea3d_add(const float* __restrict__ x, const float* __restrict__ ws,
              float* __restrict__ out)
{
    const int row = blockIdx.y;                 // b*64 + c
    const float rc = ws[WS_RC + row];
    const size_t base = (size_t)row * NTOK;
    const float4*  xp = (const float4*)(x + base);
    floatx4*       op = (floatx4*)(out + base);
    const int nvec = NTOK / 4;
    for (int i = blockIdx.x * blockDim.x + threadIdx.x; i < nvec;
         i += gridDim.x * blockDim.x) {
        float4 v = xp[i];
        floatx4 nv = { v.x + rc, v.y + rc, v.z + rc, v.w + rc };
        __builtin_nontemporal_store(nv, op + i);
    }
}

extern "C" void kernel_launch(void* const* d_in, const int* in_sizes, int n_in,
                              void* d_out, int out_size, void* d_ws, size_t ws_size,
                              hipStream_t stream)
{
    const float* x  = (const float*)d_in[0];
    const float* Wk = (const float*)d_in[1];
    // d_in[2]=bk (cancels in token-softmax); d_in[3]=Wq, d_in[4]=bq (softmax over
    // size-1 head-channel axis -> identically 1.0, so Wq/bq are dead)
    const float* Wv = (const float*)d_in[5];
    const float* bv = (const float*)d_in[6];
    const float* Wr = (const float*)d_in[7];
    const float* br = (const float*)d_in[8];
    float* out = (float*)d_out;
    float* ws  = (float*)d_ws;

    (void)hipMemsetAsync(ws, 0, WS_RC * sizeof(float), stream);  // zero S + m accumulators
    ea3d_reduce<<<dim3(GRIDX, NB), TPB, 0, stream>>>(x, Wk, ws);
    ea3d_finalize<<<1, 256, 0, stream>>>(Wv, bv, Wr, br, ws);
    ea3d_add<<<dim3(32, NB * NCH), 256, 0, stream>>>(x, ws, out);
}

// Round 14
// 165.710 us; speedup vs baseline: 2.3998x; 1.3288x over previous
//
#include <hip/hip_runtime.h>

#define NTOK 262144   // 64*64*64 tokens per batch
#define NCH  64
#define NB   4

#define TPB   512     // 8 waves
#define TILE  256     // tokens per tile; channel row = 1KB
#define GRIDX 64      // blocks per batch -> 256 total = 1/CU
#define NIT   (NTOK / (GRIDX * TILE))   // 16 tiles per block

// ws layout (floats): S[4][4] @0, m[4][4][64] @16, rc[4][64] @1040
#define WS_S  0
#define WS_M  16
#define WS_RC 1040

typedef float floatx4 __attribute__((ext_vector_type(4)));   // native vec for nontemporal
typedef const __attribute__((address_space(1))) unsigned int* gas1p;
typedef __attribute__((address_space(3))) unsigned int*       las3p;

// Single-x-read fused reduce built on async DMA (global_load_lds, width 16):
// staging costs ZERO registers, so tile t+1 streams while tile t computes —
// pipeline depth decoupled from occupancy (r5/r8/r9/r13 lesson: VGPR-funded
// prefetch always lost more in occupancy/spill than it gained).
// Per tile: vmcnt(0) + raw barrier (tile t ready; old buffer released) ->
// issue stage(t+1) -> keys from LDS (lane=1 token, 32ch half, 1 shfl) ->
// es -> lgkm+barrier -> m-phase (macc[32], static). 2 barriers/tile,
// HBM stays busy across both.
__global__ __launch_bounds__(TPB)
void ea3d_reduce(const float* __restrict__ x, const float* __restrict__ Wk,
                 float* __restrict__ ws)
{
    __shared__ __align__(16) float buf[2][NCH][TILE];   // 128KB x-tile double buffer
    __shared__ __align__(16) float es[TILE][4];         // 4KB e[t][h]
    __shared__ __align__(16) float wk4[NCH][4];         // Wk transposed
    __shared__ float ssum[8][4];

    const int tid = threadIdx.x;
    const int w   = tid >> 6;
    const int l   = tid & 63;
    const int b   = blockIdx.y;

    if (tid < 256) wk4[tid >> 2][tid & 3] = Wk[(tid & 3) * NCH + (tid >> 2)];
    __syncthreads();

    const float* xb = x + (size_t)b * NCH * NTOK;
    const size_t tokblk = (size_t)blockIdx.x * (TILE * NIT);
    const int    c0 = w << 3;                 // wave stages/m-accumulates ch 8w..8w+8

    float macc[32];                           // macc[i*4+h], channel c0+i
    #pragma unroll
    for (int r = 0; r < 32; ++r) macc[r] = 0.f;
    float sacc[4] = {0.f, 0.f, 0.f, 0.f};

    // DMA one tile's 8 channel rows for this wave: dst uniform row base,
    // src per-lane (16B/lane x 64 lanes = the full 1KB row).
    auto stage = [&](int tt) {
        const size_t t0 = tokblk + (size_t)tt * TILE + (l << 2);
        float* dbase = &buf[tt & 1][c0][0];
        #pragma unroll
        for (int i = 0; i < 8; ++i) {
            const float* src = xb + (size_t)(c0 + i) * NTOK + t0;
            float* dst = dbase + i * TILE;
            __builtin_amdgcn_global_load_lds((gas1p)src, (las3p)dst, 16, 0, 0);
        }
    };

    stage(0);                                 // prologue

    #pragma unroll 1
    for (int t = 0; t < NIT; ++t) {
        asm volatile("s_waitcnt vmcnt(0)" ::: "memory");   // tile t landed
        __builtin_amdgcn_s_barrier();                      // visible to all waves;
        asm volatile("" ::: "memory");                     // buf[(t+1)&1] released

        if (t + 1 < NIT) stage(t + 1);        // in flight across entire compute

        // ---- keys: lane token tk = w*32+(l&31), channel half (l>>5)*32 ----
        const float* bt = &buf[t & 1][0][0];
        const int tk  = (w << 5) + (l & 31);
        const int ch0 = (l >> 5) << 5;
        float k0 = 0.f, k1 = 0.f, k2 = 0.f, k3 = 0.f;
        #pragma unroll
        for (int j = 0; j < 32; ++j) {
            float  xv = bt[(ch0 + j) * TILE + tk];
            float4 wv = *(const float4*)&wk4[ch0 + j][0];
            k0 += wv.x * xv; k1 += wv.y * xv; k2 += wv.z * xv; k3 += wv.w * xv;
        }
        k0 += __shfl_xor(k0, 32); k1 += __shfl_xor(k1, 32);
        k2 += __shfl_xor(k2, 32); k3 += __shfl_xor(k3, 32);
        float e0 = __expf(k0), e1 = __expf(k1), e2 = __expf(k2), e3 = __expf(k3);
        if (l < 32) {
            *(float4*)&es[tk][0] = make_float4(e0, e1, e2, e3);
            sacc[0] += e0; sacc[1] += e1; sacc[2] += e2; sacc[3] += e3;
        }

        asm volatile("s_waitcnt lgkmcnt(0)" ::: "memory");
        __builtin_amdgcn_s_barrier();                      // es ready
        asm volatile("" ::: "memory");

        // ---- m-phase: lane tokens 4l..4l+3, wave's 8 channels, registers ----
        const int t4 = l << 2;
        float4 ea = *(const float4*)&es[t4 + 0][0];
        float4 eb = *(const float4*)&es[t4 + 1][0];
        float4 ec = *(const float4*)&es[t4 + 2][0];
        float4 ed = *(const float4*)&es[t4 + 3][0];
        #pragma unroll
        for (int i = 0; i < 8; ++i) {
            float4 xv = *(const float4*)&buf[t & 1][c0 + i][t4];
            macc[i*4+0] += ea.x*xv.x + eb.x*xv.y + ec.x*xv.z + ed.x*xv.w;
            macc[i*4+1] += ea.y*xv.x + eb.y*xv.y + ec.y*xv.z + ed.y*xv.w;
            macc[i*4+2] += ea.z*xv.x + eb.z*xv.y + ec.z*xv.z + ed.z*xv.w;
            macc[i*4+3] += ea.w*xv.x + eb.w*xv.y + ec.w*xv.z + ed.w*xv.w;
        }
    }

    // ---- macc: reduce over 64 lanes (token dim) -> 32 atomics per wave ----
    #pragma unroll
    for (int r = 0; r < 32; ++r) {
        float v = macc[r];
        v += __shfl_xor(v, 1);  v += __shfl_xor(v, 2);
        v += __shfl_xor(v, 4);  v += __shfl_xor(v, 8);
        v += __shfl_xor(v, 16); v += __shfl_xor(v, 32);
        macc[r] = v;
    }
    if (l == 0) {
        float* mb = ws + WS_M + (size_t)(b * 4) * NCH + c0;
        #pragma unroll
        for (int i = 0; i < 8; ++i) {
            #pragma unroll
            for (int h = 0; h < 4; ++h)
                __hip_atomic_fetch_add(mb + h * NCH + i, macc[i*4+h],
                                       __ATOMIC_RELAXED, __HIP_MEMORY_SCOPE_AGENT);
        }
    }

    // ---- S: lanes 0-31 hold per-token sums; reduce within the half-wave ----
    {
        float v0 = sacc[0], v1 = sacc[1], v2 = sacc[2], v3 = sacc[3];
        #pragma unroll
        for (int off = 1; off < 32; off <<= 1) {
            v0 += __shfl_xor(v0, off); v1 += __shfl_xor(v1, off);
            v2 += __shfl_xor(v2, off); v3 += __shfl_xor(v3, off);
        }
        if (l == 0) { ssum[w][0] = v0; ssum[w][1] = v1; ssum[w][2] = v2; ssum[w][3] = v3; }
    }
    __syncthreads();
    if (tid < 4) {
        float s = 0.f;
        #pragma unroll
        for (int w2 = 0; w2 < 8; ++w2) s += ssum[w2][tid];
        __hip_atomic_fetch_add(ws + WS_S + b * 4 + tid, s,
                               __ATOMIC_RELAXED, __HIP_MEMORY_SCOPE_AGENT);
    }
}

// ---------- finalize: context = Wv*(m/S)+bv ; rc = Wr*context + br ----------
__global__ void ea3d_finalize(const float* __restrict__ Wv, const float* __restrict__ bv,
                              const float* __restrict__ Wr, const float* __restrict__ br,
                              float* __restrict__ ws)
{
    __shared__ float ctx[NB * 32];
    const int tid = threadIdx.x;
    if (tid < 128) {
        int b = tid >> 5, hv = tid & 31, h = hv >> 3;
        float inv = 1.0f / ws[WS_S + b * 4 + h];
        const float* m = ws + WS_M + (b * 4 + h) * NCH;
        const float* wvr = Wv + hv * NCH;
        float acc = 0.f;
        #pragma unroll
        for (int c = 0; c < NCH; ++c) acc += wvr[c] * m[c];
        ctx[b * 32 + hv] = acc * inv + bv[hv];
    }
    __syncthreads();
    int b = tid >> 6, c = tid & 63;
    const float* wrr = Wr + c * 32;
    const float* cb  = ctx + b * 32;
    float acc = br[c];
    #pragma unroll
    for (int hv = 0; hv < 32; ++hv) acc += wrr[hv] * cb[hv];
    ws[WS_RC + b * NCH + c] = acc;
}

// ---------- out = x + rc[b][c]  (nontemporal stores: don't evict x) ----------
__global__ __launch_bounds__(256)
void ea3d_add(const float* __restrict__ x, const float* __restrict__ ws,
              float* __restrict__ out)
{
    const int row = blockIdx.y;                 // b*64 + c
    const float rc = ws[WS_RC + row];
    const size_t base = (size_t)row * NTOK;
    const float4*  xp = (const float4*)(x + base);
    floatx4*       op = (floatx4*)(out + base);
    const int nvec = NTOK / 4;
    for (int i = blockIdx.x * blockDim.x + threadIdx.x; i < nvec;
         i += gridDim.x * blockDim.x) {
        float4 v = xp[i];
        floatx4 nv = { v.x + rc, v.y + rc, v.z + rc, v.w + rc };
        __builtin_nontemporal_store(nv, op + i);
    }
}

extern "C" void kernel_launch(void* const* d_in, const int* in_sizes, int n_in,
                              void* d_out, int out_size, void* d_ws, size_t ws_size,
                              hipStream_t stream)
{
    const float* x  = (const float*)d_in[0];
    const float* Wk = (const float*)d_in[1];
    // d_in[2]=bk (cancels in token-softmax); d_in[3]=Wq, d_in[4]=bq (softmax over
    // size-1 head-channel axis -> identically 1.0, so Wq/bq are dead)
    const float* Wv = (const float*)d_in[5];
    const float* bv = (const float*)d_in[6];
    const float* Wr = (const float*)d_in[7];
    const float* br = (const float*)d_in[8];
    float* out = (float*)d_out;
    float* ws  = (float*)d_ws;

    (void)hipMemsetAsync(ws, 0, WS_RC * sizeof(float), stream);  // zero S + m accumulators
    ea3d_reduce<<<dim3(GRIDX, NB), TPB, 0, stream>>>(x, Wk, ws);
    ea3d_finalize<<<1, 256, 0, stream>>>(Wv, bv, Wr, br, ws);
    ea3d_add<<<dim3(32, NB * NCH), 256, 0, stream>>>(x, ws, out);
}